// Round 1
// baseline (118.503 us; speedup 1.0000x reference)
//
#include <hip/hip_runtime.h>
#include <hip/hip_bf16.h>

// Problem constants
#define WH 256          // 16*16
#define NB 8            // batch
#define CSLOW 1024
#define CFAST 256
#define CCAT 2048
#define COUT 1024
#define CFEAT 2048
#define NROIS 128
#define FEATSZ 4194304  // 8*2048*256
#define ROISZ  262144   // 8*16*2048

typedef short s16x8 __attribute__((ext_vector_type(8)));
typedef float f32x4 __attribute__((ext_vector_type(4)));

__device__ inline void gld_lds16(void* lds, const void* g) {
  __builtin_amdgcn_global_load_lds(
      (const __attribute__((address_space(1))) unsigned int*)g,
      (__attribute__((address_space(3))) unsigned int*)lds,
      16, 0, 0);
}

// ---------------------------------------------------------------------------
// K1: slow/fast rearrange + temporal pool (8->2 by mean of 4) + concat,
//     output transposed as FpT[col][c] bf16, col=(b*2+t)*256+wh, c in [0,2048)
// grid: b(8) * t(2) * cb(32) = 512 blocks, 256 threads
// ---------------------------------------------------------------------------
__global__ __launch_bounds__(256) void pool_transpose_kernel(
    const float* __restrict__ slow, const float* __restrict__ fast,
    __hip_bfloat16* __restrict__ FpT)
{
  __shared__ unsigned short tile[64 * 258];  // stride 258 ushort -> conflict-free phase2
  int blk = blockIdx.x;
  int b = blk >> 6;
  int rem = blk & 63;
  int t = rem >> 5;
  int cb = rem & 31;
  int tid = threadIdx.x;
  int wh = tid;
  for (int i = 0; i < 64; ++i) {
    int c = cb * 64 + i;
    float v;
    if (c < CSLOW) {
      const float* p = slow + ((size_t)(b * CSLOW + c) * 8 + 4 * t) * WH + wh;
      v = 0.25f * (p[0] + p[WH] + p[2 * WH] + p[3 * WH]);
    } else {
      int cp = c - CSLOW;
      int cf = cp & 255;
      int hi = cp >> 8;
      const float* p = fast + ((size_t)(b * CFAST + cf) * 32 + 16 * t + hi) * WH + wh;
      v = 0.25f * (p[0] + p[4 * WH] + p[8 * WH] + p[12 * WH]);
    }
    __hip_bfloat16 h = __float2bfloat16(v);
    tile[i * 258 + wh] = *(unsigned short*)&h;
  }
  __syncthreads();
  int cl = tid & 63;
  int wsub = tid >> 6;
  int col0 = (b * 2 + t) * 256;
  for (int j = 0; j < 64; ++j) {
    int whh = j * 4 + wsub;
    unsigned short u = tile[cl * 258 + whh];
    FpT[(size_t)(col0 + whh) * 2048 + cb * 64 + cl] = *(__hip_bfloat16*)&u;
  }
}

// ---------------------------------------------------------------------------
// K2: conv_w fp32 -> bf16 cast. grid 2048 x 256, 4 elems/thread
// ---------------------------------------------------------------------------
__global__ __launch_bounds__(256) void castw_kernel(
    const float* __restrict__ W, __hip_bfloat16* __restrict__ Wb)
{
  int idx = (blockIdx.x * 256 + threadIdx.x) * 4;
  float4 v = *(const float4*)(W + idx);
  Wb[idx + 0] = __float2bfloat16(v.x);
  Wb[idx + 1] = __float2bfloat16(v.y);
  Wb[idx + 2] = __float2bfloat16(v.z);
  Wb[idx + 3] = __float2bfloat16(v.w);
}

// ---------------------------------------------------------------------------
// K3: GEMM  Y[o][col] = sum_c Wb[o][c] * FpT[col][c]
// M=1024, N=4096, K=2048. Tiles BM=128 BN=64 BK=64, 256 thr (4 waves 2x2),
// global_load_lds(16B) staging with pre-swizzled source (kslot ^= row&7).
// grid (64, 8) = 512 blocks -> 2 blocks/CU.
// ---------------------------------------------------------------------------
__global__ __launch_bounds__(256) void gemm_kernel(
    const __hip_bfloat16* __restrict__ Wb,   // [1024][2048]
    const __hip_bfloat16* __restrict__ FpT,  // [4096][2048]
    float* __restrict__ Y)                   // [1024][4096]
{
  __shared__ unsigned short lA[128 * 64];
  __shared__ unsigned short lB[64 * 64];
  const int tid = threadIdx.x;
  const int lane = tid & 63;
  const int wid = tid >> 6;
  const int wm = wid >> 1, wn = wid & 1;
  const int nb = blockIdx.x, mb = blockIdx.y;
  const int lr8 = lane >> 3;   // 0..7 (row within 8-row stripe)
  const int lk  = lane & 7;    // 0..7 (16B slot)

  f32x4 acc[4][2] = {};

  for (int k0 = 0; k0 < 2048; k0 += 64) {
    __syncthreads();  // previous compute done reading LDS
    // stage A: 32 rows per wave, 4 calls x (8 rows = 1KB)
    #pragma unroll
    for (int j = 0; j < 4; ++j) {
      int row = wid * 32 + j * 8 + lr8;
      int kslot = lk ^ (row & 7);
      const __hip_bfloat16* g = Wb + (size_t)(mb * 128 + row) * 2048 + k0 + kslot * 8;
      gld_lds16(&lA[(wid * 32 + j * 8) * 64], g);
    }
    // stage B: 16 rows per wave, 2 calls
    #pragma unroll
    for (int j = 0; j < 2; ++j) {
      int row = wid * 16 + j * 8 + lr8;
      int kslot = lk ^ (row & 7);
      const __hip_bfloat16* g = FpT + (size_t)(nb * 64 + row) * 2048 + k0 + kslot * 8;
      gld_lds16(&lB[(wid * 16 + j * 8) * 64], g);
    }
    __syncthreads();  // compiler drains vmcnt before barrier

    #pragma unroll
    for (int s = 0; s < 2; ++s) {
      s16x8 af[4], bf[2];
      #pragma unroll
      for (int mi = 0; mi < 4; ++mi) {
        int row = wm * 64 + mi * 16 + (lane & 15);
        int kslot = (s * 4 + (lane >> 4)) ^ (row & 7);
        af[mi] = *(const s16x8*)((const char*)lA + (row << 7) + (kslot << 4));
      }
      #pragma unroll
      for (int ni = 0; ni < 2; ++ni) {
        int row = wn * 32 + ni * 16 + (lane & 15);
        int kslot = (s * 4 + (lane >> 4)) ^ (row & 7);
        bf[ni] = *(const s16x8*)((const char*)lB + (row << 7) + (kslot << 4));
      }
      #pragma unroll
      for (int mi = 0; mi < 4; ++mi)
        #pragma unroll
        for (int ni = 0; ni < 2; ++ni)
          acc[mi][ni] = __builtin_amdgcn_mfma_f32_16x16x32_bf16(af[mi], bf[ni], acc[mi][ni], 0, 0, 0);
    }
  }

  // epilogue: D row = o (A side), col = FpT col (B side); C/D: col=lane&15,
  // row=(lane>>4)*4+reg (m89/m91-verified mapping)
  #pragma unroll
  for (int mi = 0; mi < 4; ++mi) {
    #pragma unroll
    for (int ni = 0; ni < 2; ++ni) {
      int col = nb * 64 + wn * 32 + ni * 16 + (lane & 15);
      int o0 = mb * 128 + wm * 64 + mi * 16 + (lane >> 4) * 4;
      #pragma unroll
      for (int r = 0; r < 4; ++r)
        Y[(size_t)(o0 + r) * 4096 + col] = acc[mi][ni][r];
    }
  }
}

// ---------------------------------------------------------------------------
// K4: GroupNorm(16 groups of 64 ch, over 64*2*256=32768 elems) + ReLU,
//     write feat[b][(o*2+t)][wh] into d_out. grid 128 (b*16+g), 256 thr.
// ---------------------------------------------------------------------------
__global__ __launch_bounds__(256) void gn_kernel(
    const float* __restrict__ Y, const float* __restrict__ gamma,
    const float* __restrict__ beta, float* __restrict__ out)
{
  __shared__ float red[8];
  __shared__ float stats[2];
  int b = blockIdx.x >> 4;
  int g = blockIdx.x & 15;
  int tid = threadIdx.x;
  int ol = tid >> 2;                 // 0..63 channel-in-group
  int cseg = (tid & 3) * 128;        // 0,128,256,384 within the 512 cols of b
  const float* src = Y + (size_t)(g * 64 + ol) * 4096 + b * 512 + cseg;
  float s = 0.f, ss = 0.f;
  for (int j = 0; j < 32; ++j) {
    float4 v = *(const float4*)(src + j * 4);
    s += v.x + v.y + v.z + v.w;
    ss += v.x * v.x + v.y * v.y + v.z * v.z + v.w * v.w;
  }
  for (int off = 32; off; off >>= 1) {
    s += __shfl_xor(s, off);
    ss += __shfl_xor(ss, off);
  }
  int lane = tid & 63, wid = tid >> 6;
  if (lane == 0) { red[wid] = s; red[wid + 4] = ss; }
  __syncthreads();
  if (tid == 0) {
    float S = red[0] + red[1] + red[2] + red[3];
    float SS = red[4] + red[5] + red[6] + red[7];
    float mu = S / 32768.f;
    float var = SS / 32768.f - mu * mu;
    stats[0] = mu;
    stats[1] = 1.0f / sqrtf(var + 1e-5f);
  }
  __syncthreads();
  float mu = stats[0], rstd = stats[1];
  int o = g * 64 + ol;
  float ga = gamma[o], be = beta[o];
  int tpool = cseg >> 8;
  int wh0 = cseg & 255;
  float* dst = out + ((size_t)(b * 2048 + o * 2 + tpool)) * 256 + wh0;
  for (int j = 0; j < 32; ++j) {
    float4 v = *(const float4*)(src + j * 4);
    float4 r;
    r.x = fmaxf((v.x - mu) * rstd * ga + be, 0.f);
    r.y = fmaxf((v.y - mu) * rstd * ga + be, 0.f);
    r.z = fmaxf((v.z - mu) * rstd * ga + be, 0.f);
    r.w = fmaxf((v.w - mu) * rstd * ga + be, 0.f);
    *(float4*)(dst + j * 4) = r;
  }
}

// ---------------------------------------------------------------------------
// K5: wbar[n][q] = (1/256) sum_p Wmat[n,p,q]  (mmcv RoIAlign aligned=true,
// ratio=2, avg; includes the /4 sample count and /256 output-mean).
// grid 128 (one per roi), 256 thr (one per output point).
// ---------------------------------------------------------------------------
__global__ __launch_bounds__(256) void wbar_kernel(
    const float* __restrict__ rois, float* __restrict__ wbar)
{
  __shared__ float acc[256];
  int n = blockIdx.x;
  int tid = threadIdx.x;
  acc[tid] = 0.f;
  __syncthreads();
  const float* r = rois + n * 5;
  float x1 = r[1] * (1.f / 16.f) - 0.5f;
  float y1 = r[2] * (1.f / 16.f) - 0.5f;
  float x2 = r[3] * (1.f / 16.f) - 0.5f;
  float y2 = r[4] * (1.f / 16.f) - 0.5f;
  float bw = (x2 - x1) / 16.f;
  float bh = (y2 - y1) / 16.f;
  int py = tid >> 4, px = tid & 15;
  #pragma unroll
  for (int sy = 0; sy < 2; ++sy) {
    #pragma unroll
    for (int sx = 0; sx < 2; ++sx) {
      float gy = (float)py + (sy + 0.5f) * 0.5f;
      float gx = (float)px + (sx + 0.5f) * 0.5f;
      float Yv = y1 + gy * bh;
      float Xv = x1 + gx * bw;
      if (Yv >= -1.f && Yv <= 16.f && Xv >= -1.f && Xv <= 16.f) {
        float y = fmaxf(Yv, 0.f);
        float x = fmaxf(Xv, 0.f);
        float y0f = floorf(y);
        float x0f = floorf(x);
        bool ye = y0f >= 15.f;
        bool xe = x0f >= 15.f;
        int y0 = ye ? 15 : (int)y0f;
        int y1i = ye ? 15 : y0 + 1;
        int x0 = xe ? 15 : (int)x0f;
        int x1i = xe ? 15 : x0 + 1;
        float ly = ye ? 0.f : (y - y0f);
        float lx = xe ? 0.f : (x - x0f);
        float hy = 1.f - ly, hx = 1.f - lx;
        atomicAdd(&acc[y0 * 16 + x0], hy * hx);
        atomicAdd(&acc[y0 * 16 + x1i], hy * lx);
        atomicAdd(&acc[y1i * 16 + x0], ly * hx);
        atomicAdd(&acc[y1i * 16 + x1i], ly * lx);
      }
    }
  }
  __syncthreads();
  wbar[n * 256 + tid] = acc[tid] * (1.f / 1024.f);  // /4 samples /256 points
}

// ---------------------------------------------------------------------------
// K6: roi_feat[n][c] = sum_q wbar[n][q] feat[b][c][q];
//     roi_pos [n][c] = sum_q wbar[n][q] pos[c][q].
// grid 128 = b(8) x chunk(16 of 128 ch); 256 thr = 128 ch x 2 q-halves.
// feat value loaded once, reused for all 16 rois of the clip.
// ---------------------------------------------------------------------------
__global__ __launch_bounds__(256) void roi_kernel(
    const float* __restrict__ feat, const float* __restrict__ pos,
    const float* __restrict__ wbar, float* __restrict__ out)
{
  __shared__ float wl[16][256];
  __shared__ float sF[2][16][128];
  __shared__ float sP[2][16][128];
  int b = blockIdx.x >> 4;
  int chunk = blockIdx.x & 15;
  int tid = threadIdx.x;
  #pragma unroll
  for (int rr = 0; rr < 16; ++rr)
    wl[rr][tid] = wbar[(b * 16 + rr) * 256 + tid];
  __syncthreads();
  int ch_l = tid & 127;
  int half = tid >> 7;
  int ch = chunk * 128 + ch_l;
  const float* fb = feat + ((size_t)(b * 2048 + ch)) * 256 + half * 128;
  const float* pb = pos + (size_t)ch * 256 + half * 128;
  float accF[16] = {0.f}, accP[16] = {0.f};
  for (int q0 = 0; q0 < 128; q0 += 4) {
    float4 vf = *(const float4*)(fb + q0);
    float4 vp = *(const float4*)(pb + q0);
    int q = half * 128 + q0;
    #pragma unroll
    for (int rr = 0; rr < 16; ++rr) {
      float4 w = *(const float4*)&wl[rr][q];
      accF[rr] += w.x * vf.x + w.y * vf.y + w.z * vf.z + w.w * vf.w;
      accP[rr] += w.x * vp.x + w.y * vp.y + w.z * vp.z + w.w * vp.w;
    }
  }
  #pragma unroll
  for (int rr = 0; rr < 16; ++rr) {
    sF[half][rr][ch_l] = accF[rr];
    sP[half][rr][ch_l] = accP[rr];
  }
  __syncthreads();
  if (half == 0) {
    #pragma unroll
    for (int rr = 0; rr < 16; ++rr) {
      float vF = sF[0][rr][ch_l] + sF[1][rr][ch_l];
      float vP = sP[0][rr][ch_l] + sP[1][rr][ch_l];
      out[FEATSZ + (size_t)(b * 16 + rr) * 2048 + ch] = vF;
      out[FEATSZ + ROISZ + (size_t)(b * 16 + rr) * 2048 + ch] = vP;
    }
  }
}

// ---------------------------------------------------------------------------
extern "C" void kernel_launch(void* const* d_in, const int* in_sizes, int n_in,
                              void* d_out, int out_size, void* d_ws, size_t ws_size,
                              hipStream_t stream)
{
  (void)in_sizes; (void)n_in; (void)out_size; (void)ws_size;
  const float* slow   = (const float*)d_in[0];
  const float* fast   = (const float*)d_in[1];
  const float* rois   = (const float*)d_in[2];
  const float* pos    = (const float*)d_in[3];
  const float* conv_w = (const float*)d_in[4];
  const float* gamma  = (const float*)d_in[5];
  const float* beta   = (const float*)d_in[6];
  float* out = (float*)d_out;
  char* ws = (char*)d_ws;

  __hip_bfloat16* FpT = (__hip_bfloat16*)(ws);                       // 16 MB: [4096][2048] bf16
  __hip_bfloat16* Wb  = (__hip_bfloat16*)(ws + 16777216);            // 4 MB:  [1024][2048] bf16
  float* Y            = (float*)(ws + 16777216 + 4194304);           // 16 MB: [1024][4096] f32
  float* wbar         = (float*)(ws + 16777216 + 4194304 + 16777216);// 128KB: [128][256] f32

  pool_transpose_kernel<<<dim3(512), dim3(256), 0, stream>>>(slow, fast, FpT);
  castw_kernel<<<dim3(2048), dim3(256), 0, stream>>>(conv_w, Wb);
  gemm_kernel<<<dim3(64, 8), dim3(256), 0, stream>>>(Wb, FpT, Y);
  gn_kernel<<<dim3(128), dim3(256), 0, stream>>>(Y, gamma, beta, out);
  wbar_kernel<<<dim3(128), dim3(256), 0, stream>>>(rois, wbar);
  roi_kernel<<<dim3(128), dim3(256), 0, stream>>>(out, pos, wbar, out);
}